// Round 9
// baseline (317.940 us; speedup 1.0000x reference)
//
#include <hip/hip_runtime.h>
#include <hip/hip_bf16.h>
#include <math.h>

#define NB 2        // batch
#define NC 64       // channels
#define ND 8        // head dim (C/8)
#define NN 4096     // tokens (T*W*H)
#define NM 256      // landmarks
#define NL 16       // N/M
#define SCALE 0.35355339059327373f  // 1/sqrt(8)
// p(z) = 13-15z+7z^2-z^3 = (A_ROOT - z)(z^2 + B_COEF z + C_COEF)  [validated R7/R8]
#define A_ROOT 4.1303956f
#define B_COEF (-2.8696044f)
#define C_COEF 3.1474086f

typedef __attribute__((ext_vector_type(4))) float f32x4;
typedef __attribute__((ext_vector_type(8))) short bf16x8;
typedef __attribute__((ext_vector_type(4))) short bf16x4;

__device__ inline ushort f2bf(float f) {
  __hip_bfloat16 h = __float2bfloat16(f);
  return *reinterpret_cast<ushort*>(&h);
}
__device__ inline float bf2f(ushort u) {
  return __uint_as_float(((unsigned int)u) << 16);
}

// async global->LDS, 16B per lane; LDS dest must be wave-linear (base + lane*16)
__device__ inline void gl_lds16(const void* g, void* l) {
  __builtin_amdgcn_global_load_lds(
      (const __attribute__((address_space(1))) unsigned int*)g,
      (__attribute__((address_space(3))) unsigned int*)l, 16, 0, 0);
}

__device__ inline unsigned lds_addr(const void* p) {
  return (unsigned)(size_t)(__attribute__((address_space(3))) const void*)p;
}

// ---------------- qkv projection, output-row parallel (R5) ----------------
__global__ __launch_bounds__(256) void qkv2_kernel(
    const float* __restrict__ x,
    const float* __restrict__ wq, const float* __restrict__ bq,
    const float* __restrict__ wk, const float* __restrict__ bk,
    const float* __restrict__ wv, const float* __restrict__ bv,
    float* __restrict__ q, float* __restrict__ k, float* __restrict__ v) {
  __shared__ float ws[NC];
  int o = blockIdx.x;            // 0..79: 0-7 q, 8-15 k, 16-79 v
  int b = blockIdx.z;
  int n0 = blockIdx.y * 1024;
  int t = threadIdx.x;
  const float* wrow;
  float bias;
  if (o < ND)            { wrow = wq + (size_t)o * NC;            bias = bq[o]; }
  else if (o < 2 * ND)   { wrow = wk + (size_t)(o - ND) * NC;     bias = bk[o - ND]; }
  else                   { wrow = wv + (size_t)(o - 2 * ND) * NC; bias = bv[o - 2 * ND]; }
  if (t < NC) ws[t] = wrow[t];
  __syncthreads();
  int n = n0 + t * 4;
  float4 acc = {bias, bias, bias, bias};
  #pragma unroll
  for (int c = 0; c < NC; ++c) {
    float wc = ws[c];
    float4 xv = *(const float4*)(x + ((size_t)b * NC + c) * NN + n);
    acc.x += wc * xv.x; acc.y += wc * xv.y; acc.z += wc * xv.z; acc.w += wc * xv.w;
  }
  if (o < ND) {
    float* qp = q + ((size_t)b * NN + n) * ND + o;
    qp[0] = acc.x; qp[8] = acc.y; qp[16] = acc.z; qp[24] = acc.w;
  } else if (o < 2 * ND) {
    float* kp = k + ((size_t)b * NN + n) * ND + (o - ND);
    kp[0] = acc.x; kp[8] = acc.y; kp[16] = acc.z; kp[24] = acc.w;
  } else {
    *(float4*)(v + ((size_t)b * NC + (o - 2 * ND)) * NN + n) = acc;
  }
}

// ---------------- landmarks (R5) ----------------
__global__ void landmark_kernel(const float* __restrict__ q, const float* __restrict__ k,
                                float* __restrict__ ql, float* __restrict__ kl) {
  int idx = blockIdx.x * 256 + threadIdx.x;
  int b = idx / (NM * ND), r = idx % (NM * ND), i = r / ND, o = r % ND;
  float sq = 0.f, sk = 0.f;
  for (int l = 0; l < NL; ++l) {
    size_t base = ((size_t)b * NN + i * NL + l) * ND + o;
    sq += q[base]; sk += k[base];
  }
  ql[idx] = sq * (1.0f / NL);
  kl[idx] = sk * (1.0f / NL);
}

// ---------------- softmax rows vs landmarks: bf16 output (k1) ----------------
__global__ __launch_bounds__(256) void scores_softmax_m_bf16(
    const float* __restrict__ Q, int R, const float* __restrict__ KL,
    ushort* __restrict__ out) {
  __shared__ float skl[NM][9];
  int b = blockIdx.y;
  int t = threadIdx.x;
  for (int i = t; i < NM * ND; i += 256) skl[i >> 3][i & 7] = KL[(size_t)b * NM * ND + i];
  __syncthreads();
  int wave = t >> 6, lane = t & 63;
  int r = blockIdx.x * 4 + wave;
  const float* qrow = Q + ((size_t)b * R + r) * ND;
  float qr[ND];
  #pragma unroll
  for (int dd = 0; dd < ND; ++dd) qr[dd] = qrow[dd];
  float sc[4];
  float lmax = -1e30f;
  #pragma unroll
  for (int s = 0; s < 4; ++s) {
    int j = lane + 64 * s;
    float a = 0.f;
    #pragma unroll
    for (int dd = 0; dd < ND; ++dd) a += qr[dd] * skl[j][dd];
    sc[s] = a * SCALE;
    lmax = fmaxf(lmax, sc[s]);
  }
  for (int off = 32; off; off >>= 1) lmax = fmaxf(lmax, __shfl_xor(lmax, off));
  float lsum = 0.f;
  #pragma unroll
  for (int s = 0; s < 4; ++s) { sc[s] = expf(sc[s] - lmax); lsum += sc[s]; }
  for (int off = 32; off; off >>= 1) lsum += __shfl_xor(lsum, off);
  float inv = 1.0f / lsum;
  #pragma unroll
  for (int s = 0; s < 4; ++s)
    out[((size_t)b * R + r) * NM + lane + 64 * s] = f2bf(sc[s] * inv);
}

// ---------------- softmax rows vs landmarks: fp32 output (k2) ----------------
__global__ __launch_bounds__(256) void scores_softmax_m_f32(
    const float* __restrict__ Q, int R, const float* __restrict__ KL,
    float* __restrict__ out) {
  __shared__ float skl[NM][9];
  int b = blockIdx.y;
  int t = threadIdx.x;
  for (int i = t; i < NM * ND; i += 256) skl[i >> 3][i & 7] = KL[(size_t)b * NM * ND + i];
  __syncthreads();
  int wave = t >> 6, lane = t & 63;
  int r = blockIdx.x * 4 + wave;
  const float* qrow = Q + ((size_t)b * R + r) * ND;
  float qr[ND];
  #pragma unroll
  for (int dd = 0; dd < ND; ++dd) qr[dd] = qrow[dd];
  float sc[4];
  float lmax = -1e30f;
  #pragma unroll
  for (int s = 0; s < 4; ++s) {
    int j = lane + 64 * s;
    float a = 0.f;
    #pragma unroll
    for (int dd = 0; dd < ND; ++dd) a += qr[dd] * skl[j][dd];
    sc[s] = a * SCALE;
    lmax = fmaxf(lmax, sc[s]);
  }
  for (int off = 32; off; off >>= 1) lmax = fmaxf(lmax, __shfl_xor(lmax, off));
  float lsum = 0.f;
  #pragma unroll
  for (int s = 0; s < 4; ++s) { sc[s] = expf(sc[s] - lmax); lsum += sc[s]; }
  for (int off = 32; off; off >>= 1) lsum += __shfl_xor(lsum, off);
  float inv = 1.0f / lsum;
  #pragma unroll
  for (int s = 0; s < 4; ++s) out[((size_t)b * R + r) * NM + lane + 64 * s] = sc[s] * inv;
}

// ---------------- k3 softmax -> bf16 row-major [M][N] ----------------
__global__ __launch_bounds__(256) void scores_softmax_n(
    const float* __restrict__ QL, const float* __restrict__ Kt,
    ushort* __restrict__ out) {
  __shared__ float wred[4], wsum[4];
  int b = blockIdx.y, i = blockIdx.x;
  int t = threadIdx.x;
  float qr[ND];
  #pragma unroll
  for (int dd = 0; dd < ND; ++dd) qr[dd] = QL[((size_t)b * NM + i) * ND + dd];
  float sc[16];
  float lmax = -1e30f;
  #pragma unroll
  for (int s = 0; s < 16; ++s) {
    int n = t + 256 * s;
    const float* kp = Kt + ((size_t)b * NN + n) * ND;
    float a = 0.f;
    #pragma unroll
    for (int dd = 0; dd < ND; ++dd) a += qr[dd] * kp[dd];
    sc[s] = a * SCALE;
    lmax = fmaxf(lmax, sc[s]);
  }
  for (int off = 32; off; off >>= 1) lmax = fmaxf(lmax, __shfl_xor(lmax, off));
  if ((t & 63) == 0) wred[t >> 6] = lmax;
  __syncthreads();
  lmax = fmaxf(fmaxf(wred[0], wred[1]), fmaxf(wred[2], wred[3]));
  float lsum = 0.f;
  #pragma unroll
  for (int s = 0; s < 16; ++s) { sc[s] = expf(sc[s] - lmax); lsum += sc[s]; }
  for (int off = 32; off; off >>= 1) lsum += __shfl_xor(lsum, off);
  if ((t & 63) == 0) wsum[t >> 6] = lsum;
  __syncthreads();
  lsum = wsum[0] + wsum[1] + wsum[2] + wsum[3];
  float inv = 1.0f / lsum;
  #pragma unroll
  for (int s = 0; s < 16; ++s)
    out[((size_t)b * NM + i) * NN + t + 256 * s] = f2bf(sc[s] * inv);
}

// ---------------- denom: max column-sum per batch ----------------
__global__ __launch_bounds__(256) void denom_kernel(const float* __restrict__ k2,
                                                    float* __restrict__ denw) {
  __shared__ float red[256];
  int b = blockIdx.x;
  int t = threadIdx.x;
  float cs = 0.f;
  for (int i = 0; i < NM; ++i) cs += k2[((size_t)b * NM + i) * NM + t];
  red[t] = cs;
  __syncthreads();
  for (int off = 128; off; off >>= 1) {
    if (t < off) red[t] = fmaxf(red[t], red[t + off]);
    __syncthreads();
  }
  if (t == 0) denw[b] = red[0];
}

// ---------------- V0 = k2^T * invdenom ----------------
__global__ void vinit_kernel(const float* __restrict__ k2, const float* __restrict__ denw,
                             float* __restrict__ V) {
  int idx = blockIdx.x * 256 + threadIdx.x;
  int b = idx / (NM * NM), r = idx % (NM * NM), i = r / NM, j = r % NM;
  float dval = 1.0f / fmaxf(denw[0], denw[1]);
  V[idx] = k2[((size_t)b * NM + j) * NM + i] * dval;
}

// ================= NS: factored cubic, 3 homogeneous launches / iter ==========
#define NS_SMEM 70144   // As 32x260x4 (33280) + Bs 256x36x4 (36864)

// 32x32 output tile, full K=256, single barrier (R5 gemm_rk32 structure).
// B2 == nullptr: B plain.  B2 != nullptr: B_eff = B + B_COEF*B2 + C_COEF*I.
// O = s_ab * (A @ B_eff) + s_a * A
__device__ __forceinline__ void ns_tile(
    const float* __restrict__ A, const float* __restrict__ B,
    const float* __restrict__ B2, float* __restrict__ O,
    float s_a, float s_ab, size_t bo, int bi, int bj, char* smem, int t) {
  typedef float ARow[260];
  typedef float BRow[36];
  ARow* As = (ARow*)smem;
  BRow* Bs = (BRow*)(smem + 33280);
  #pragma unroll
  for (int q = 0; q < 8; ++q) {
    int s = q * 256 + t;
    int ar = s >> 6, ac = (s & 63) * 4;
    *(float4*)&As[ar][ac] = *(const float4*)(A + bo + (size_t)(bi + ar) * NM + ac);
    int bk = s >> 3, bc = (s & 7) * 4;
    if (B2 == nullptr) {
      *(float4*)&Bs[bk][bc] = *(const float4*)(B + bo + (size_t)bk * NM + bj + bc);
    } else {
      float4 v = *(const float4*)(B + bo + (size_t)bk * NM + bj + bc);
      float4 z = *(const float4*)(B2 + bo + (size_t)bk * NM + bj + bc);
      float4 rr;
      rr.x = v.x + B_COEF * z.x; rr.y = v.y + B_COEF * z.y;
      rr.z = v.z + B_COEF * z.z; rr.w = v.w + B_COEF * z.w;
      int d = bk - bj - bc;
      if (d >= 0 && d < 4) ((float*)&rr)[d] += C_COEF;
      *(float4*)&Bs[bk][bc] = rr;
    }
  }
  __syncthreads();
  int tx = t & 15, ty = t >> 4;
  float acc[2][2] = {};
  #pragma unroll 8
  for (int kk = 0; kk < NM; ++kk) {
    float a0 = As[ty * 2][kk], a1 = As[ty * 2 + 1][kk];
    float b0 = Bs[kk][tx * 2], b1 = Bs[kk][tx * 2 + 1];
    acc[0][0] += a0 * b0; acc[0][1] += a0 * b1;
    acc[1][0] += a1 * b0; acc[1][1] += a1 * b1;
  }
  #pragma unroll
  for (int i = 0; i < 2; ++i)
    #pragma unroll
    for (int j = 0; j < 2; ++j) {
      size_t o = bo + (size_t)(bi + ty * 2 + i) * NM + bj + tx * 2 + j;
      float r = s_ab * acc[i][j];
      if (s_a != 0.0f) r += s_a * A[o];
      O[o] = r;
    }
}

// Z = k2 @ V
__global__ __launch_bounds__(256) void ns_z_kernel(
    const float* __restrict__ k2, const float* __restrict__ V, float* __restrict__ Z) {
  __shared__ char smem[NS_SMEM];
  int blk = blockIdx.x, t = threadIdx.x;
  int b = blk >> 6, tile = blk & 63;
  int bi = (tile >> 3) * 32, bj = (tile & 7) * 32;
  ns_tile(k2, V, nullptr, Z, 0.f, 1.f, (size_t)b * NM * NM, bi, bj, smem, t);
}

// dual: blk<128 -> U = V@Z - a*V ; else -> Z2 = Z@Z
__global__ __launch_bounds__(256) void ns_uz2_kernel(
    const float* __restrict__ V, const float* __restrict__ Z,
    float* __restrict__ U, float* __restrict__ Z2) {
  __shared__ char smem[NS_SMEM];
  int blk = blockIdx.x, t = threadIdx.x;
  if (blk < NB * 64) {
    int b = blk >> 6, tile = blk & 63;
    int bi = (tile >> 3) * 32, bj = (tile & 7) * 32;
    ns_tile(V, Z, nullptr, U, -A_ROOT, 1.f, (size_t)b * NM * NM, bi, bj, smem, t);
  } else {
    int r = blk - NB * 64;
    int b = r >> 6, tile = r & 63;
    int bi = (tile >> 3) * 32, bj = (tile & 7) * 32;
    ns_tile(Z, Z, nullptr, Z2, 0.f, 1.f, (size_t)b * NM * NM, bi, bj, smem, t);
  }
}

// V' = -0.25 * U @ (Z2 + B_COEF*Z + C_COEF*I)
__global__ __launch_bounds__(256) void ns_v_kernel(
    const float* __restrict__ U, const float* __restrict__ Z2,
    const float* __restrict__ Z, float* __restrict__ Vout) {
  __shared__ char smem[NS_SMEM];
  int blk = blockIdx.x, t = threadIdx.x;
  int b = blk >> 6, tile = blk & 63;
  int bi = (tile >> 3) * 32, bj = (tile & 7) * 32;
  ns_tile(U, Z2, Z, Vout, 0.f, -0.25f, (size_t)b * NM * NM, bi, bj, smem, t);
}

// ---------------- Vinv fp32 -> bf16 transposed (R5) ----------------
__global__ __launch_bounds__(256) void cvt_vinv_kernel(const float* __restrict__ Va,
                                                       ushort* __restrict__ Vt) {
  int b = blockIdx.z;
  int n0 = blockIdx.x * 32, m0 = blockIdx.y * 32;
  __shared__ float tile[32][33];
  int t = threadIdx.x;
  int r = t >> 3, c4 = (t & 7) * 4;
  float4 v = *(const float4*)(Va + ((size_t)b * NM + m0 + r) * NM + n0 + c4);
  tile[c4][r] = v.x; tile[c4 + 1][r] = v.y; tile[c4 + 2][r] = v.z; tile[c4 + 3][r] = v.w;
  __syncthreads();
  ushort4 u;
  u.x = f2bf(tile[r][c4]);     u.y = f2bf(tile[r][c4 + 1]);
  u.z = f2bf(tile[r][c4 + 2]); u.w = f2bf(tile[r][c4 + 3]);
  *(ushort4*)(Vt + ((size_t)b * NM + n0 + r) * NM + m0 + c4) = u;
}

// ---------------- A = k1 @ Vinv via bf16 MFMA (R5) ----------------
__global__ __launch_bounds__(256) void gemm_a_mfma(
    const ushort* __restrict__ k1bf, const ushort* __restrict__ Vt,
    ushort* __restrict__ Abf) {
  int b = blockIdx.z;
  int bi = blockIdx.y * 128, bj = blockIdx.x * 128;
  __shared__ ushort As[128 * 64];
  __shared__ ushort Bs[128 * 64];
  int t = threadIdx.x;
  int wave = t >> 6, lane = t & 63;
  int wr = wave >> 1, wc = wave & 1;
  const ushort* Ab = k1bf + (size_t)b * NN * NM;
  const ushort* Bb = Vt + (size_t)b * NM * NM;
  f32x4 acc[4][4] = {};
  for (int k0 = 0; k0 < NM; k0 += 64) {
    #pragma unroll
    for (int q = 0; q < 4; ++q) {
      int s = q * 256 + t;
      int r = s >> 3, c = s & 7;
      int cs = (c ^ (r & 7)) << 3;
      gl_lds16(Ab + (size_t)(bi + r) * NM + k0 + cs, As + (size_t)s * 8);
      gl_lds16(Bb + (size_t)(bj + r) * NM + k0 + cs, Bs + (size_t)s * 8);
    }
    __syncthreads();
    #pragma unroll
    for (int kk = 0; kk < 2; ++kk) {
      int koff = kk * 64 + (lane >> 4) * 16;
      bf16x8 af[4], bfv[4];
      #pragma unroll
      for (int mi = 0; mi < 4; ++mi) {
        int row = wr * 64 + mi * 16 + (lane & 15);
        af[mi] = *(const bf16x8*)((const char*)As + row * 128 + (koff ^ ((row & 7) << 4)));
      }
      #pragma unroll
      for (int nj = 0; nj < 4; ++nj) {
        int row = wc * 64 + nj * 16 + (lane & 15);
        bfv[nj] = *(const bf16x8*)((const char*)Bs + row * 128 + (koff ^ ((row & 7) << 4)));
      }
      #pragma unroll
      for (int mi = 0; mi < 4; ++mi)
        #pragma unroll
        for (int nj = 0; nj < 4; ++nj)
          acc[mi][nj] = __builtin_amdgcn_mfma_f32_16x16x32_bf16(af[mi], bfv[nj], acc[mi][nj], 0, 0, 0);
    }
    __syncthreads();
  }
  int col = lane & 15, rbase = (lane >> 4) * 4;
  #pragma unroll
  for (int mi = 0; mi < 4; ++mi)
    #pragma unroll
    for (int nj = 0; nj < 4; ++nj)
      #pragma unroll
      for (int r = 0; r < 4; ++r)
        Abf[((size_t)b * NN + bi + wr * 64 + mi * 16 + rbase + r) * NM
            + bj + wc * 64 + nj * 16 + col] = f2bf(acc[mi][nj][r]);
}

// ---------------- attn = A @ k3 via bf16 MFMA; B from k3bf [M][N] via tr-read ----------------
// B LDS layout: 8 panels (16 cols each); panel = [64 k][16 col] bf16 row-major (k-pitch 32B).
// ds_read_b64_tr_b16 semantics [m156/m162]: lane reads 4 bf16 at addr + {0,32,64,96} B.
__global__ __launch_bounds__(256) void gemm_attn_mfma(
    const ushort* __restrict__ Abf, const ushort* __restrict__ k3bf,
    float* __restrict__ attn) {
  int lin = blockIdx.z * 1024 + blockIdx.y * 32 + blockIdx.x;
  int swz = (lin & 7) * 256 + (lin >> 3);   // bijective XCD swizzle (2048 % 8 == 0)
  int b = swz >> 10;
  int rem = swz & 1023;
  int bi = (rem >> 5) * 128, bj = (rem & 31) * 128;
  __shared__ ushort As[128 * 64];   // 16KB, XOR-swizzled rows (A path, unchanged)
  __shared__ ushort Bs[8 * 64 * 16];  // 16KB, 8 sub-panels for tr-read
  int t = threadIdx.x;
  int wave = t >> 6, lane = t & 63;
  int wr = wave >> 1, wc = wave & 1;
  const ushort* Ab = Abf + (size_t)b * NN * NM;     // [N][M] k-contig
  const ushort* Bb = k3bf + (size_t)b * NM * NN;    // [M=k][N]
  f32x4 acc[4][4] = {};
  unsigned bs_base = lds_addr(&Bs[0]);
  unsigned trlane = (unsigned)((lane & 15) * 2 + (lane >> 4) * 256);
  for (int k0 = 0; k0 < NM; k0 += 64) {
    #pragma unroll
    for (int q = 0; q < 4; ++q) {
      int s = q * 256 + t;
      // A: row r, 16B chunk c, pre-swizzled global source, linear LDS dest
      int r = s >> 3, c = s & 7;
      int cs = (c ^ (r & 7)) << 3;
      gl_lds16(Ab + (size_t)(bi + r) * NM + k0 + cs, As + (size_t)s * 8);
      // B: panel cq, k-row kk2, 8-col half hf; contiguous 16B global source
      int cq = s >> 7, kk2 = (s >> 1) & 63, hf = s & 1;
      gl_lds16(Bb + (size_t)(k0 + kk2) * NN + bj + cq * 16 + hf * 8,
               Bs + (size_t)s * 8);
    }
    __syncthreads();
    #pragma unroll
    for (int kk = 0; kk < 2; ++kk) {
      int koff = kk * 64 + (lane >> 4) * 16;
      bf16x8 af[4], bfv[4];
      #pragma unroll
      for (int mi = 0; mi < 4; ++mi) {
        int row = wr * 64 + mi * 16 + (lane & 15);
        af[mi] = *(const bf16x8*)((const char*)As + row * 128 + (koff ^ ((row & 7) << 4)));
      }
      #pragma unroll
      for (int nj = 0; nj < 4; ++nj) {
        int cq = wc * 4 + nj;
        unsigned a32 = bs_base + (unsigned)(cq * 2048 + kk * 1024) + trlane;
        bf16x4 lo, hi;
        asm volatile("ds_read_b64_tr_b16 %0, %2 offset:0\n\t"
                     "ds_read_b64_tr_b16 %1, %2 offset:128"
                     : "=&v"(lo), "=&v"(hi) : "v"(a32));
        bfv[nj] = __builtin_shufflevector(lo, hi, 0, 1, 2, 3, 4, 5, 6, 7);
      }
      asm volatile("s_waitcnt lgkmcnt(0)" ::: "memory");
      __builtin_amdgcn_sched_barrier(0);   // rule #18: fence MFMA hoisting
      #pragma unroll
      for (int mi = 0; mi < 4; ++mi)
        #pragma unroll
        for (int nj = 0; nj < 4; ++nj)
          acc[mi][nj] = __builtin_amdgcn_mfma_f32_16x16x32_bf16(af[mi], bfv[nj], acc[mi][nj], 0, 0, 0);
    }
    __syncthreads();
  }
  int col = lane & 15, rbase = (lane >> 4) * 4;
  #pragma unroll
  for (int mi = 0; mi < 4; ++mi)
    #pragma unroll
    for (int nj = 0; nj < 4; ++nj)
      #pragma unroll
      for (int r = 0; r < 4; ++r)
        attn[((size_t)b * NN + bi + wr * 64 + mi * 16 + rbase + r) * NN
             + bj + wc * 64 + nj * 16 + col] = acc[mi][nj][r];
}

// ---------------- split-K kv (k3 in bf16, atomicAdd into zeroed buffer) ----------------
__global__ __launch_bounds__(256) void kv_kernel(
    const ushort* __restrict__ K3, const float* __restrict__ Vv,
    float* __restrict__ kvout) {
  int b = blockIdx.z, bp = blockIdx.x * 64;
  int j0base = blockIdx.y * (NN / 32);
  __shared__ float Ks[64][33], Vs[64][33];
  int t = threadIdx.x, tx = t & 15, ty = t >> 4;
  int lrow = t >> 2, ljc = (t & 3) * 8;
  float acc[4][4] = {};
  for (int j0 = j0base; j0 < j0base + NN / 32; j0 += 32) {
    bf16x8 a0 = *(const bf16x8*)(K3 + ((size_t)b * NM + bp + lrow) * NN + j0 + ljc);
    float4 v0 = *(const float4*)(Vv + ((size_t)b * NC + lrow) * NN + j0 + ljc);
    float4 v1 = *(const float4*)(Vv + ((size_t)b * NC + lrow) * NN + j0 + ljc + 4);
    #pragma unroll
    for (int e = 0; e < 8; ++e) Ks[lrow][ljc + e] = bf2f((ushort)a0[e]);
    Vs[lrow][ljc + 0] = v0.x; Vs[lrow][ljc + 1] = v0.y; Vs[lrow][ljc + 2] = v0.z; Vs[lrow][ljc + 3] = v0.w;
    Vs[lrow][ljc + 4] = v1.x; Vs[lrow][ljc + 5] = v1.y; Vs[lrow][ljc + 6] = v1.z; Vs[lrow][ljc + 7] = v1.w;
    __syncthreads();
    #pragma unroll
    for (int kk = 0; kk < 32; ++kk) {
      float av_[4], bv_[4];
      #pragma unroll
      for (int i = 0; i < 4; ++i) av_[i] = Ks[(ty << 2) + i][kk];
      #pragma unroll
      for (int j = 0; j < 4; ++j) bv_[j] = Vs[(tx << 2) + j][kk];
      #pragma unroll
      for (int i = 0; i < 4; ++i)
        #pragma unroll
        for (int j = 0; j < 4; ++j) acc[i][j] += av_[i] * bv_[j];
    }
    __syncthreads();
  }
  #pragma unroll
  for (int i = 0; i < 4; ++i)
    #pragma unroll
    for (int j = 0; j < 4; ++j)
      atomicAdd(&kvout[((size_t)b * NM + bp + (ty << 2) + i) * NC + (tx << 2) + j], acc[i][j]);
}

// ---------------- out = gamma*(A@kv) + x  (A in bf16, R5) ----------------
__global__ __launch_bounds__(256) void out_kernel(
    const ushort* __restrict__ Abf, const float* __restrict__ kvm,
    const float* __restrict__ x, const float* __restrict__ gamma,
    float* __restrict__ outp) {
  __shared__ float As[32 * 256];
  int blk = blockIdx.x;
  int b = blk / (NN / 32), n0 = (blk % (NN / 32)) * 32;
  int t = threadIdx.x;
  for (int it = 0; it < 32; ++it)
    As[it * 256 + (t ^ (it & 31))] = bf2f(Abf[((size_t)b * NN + n0 + it) * NM + t]);
  __syncthreads();
  int tn = t & 31, cg0 = (t >> 5) * 8;
  float g = gamma[0];
  float acc[8] = {};
  for (int p = 0; p < NM; ++p) {
    float a = As[tn * 256 + (p ^ (tn & 31))];
    float4 kv0 = *(const float4*)(kvm + ((size_t)b * NM + p) * NC + cg0);
    float4 kv1 = *(const float4*)(kvm + ((size_t)b * NM + p) * NC + cg0 + 4);
    acc[0] += a * kv0.x; acc[1] += a * kv0.y; acc[2] += a * kv0.z; acc[3] += a * kv0.w;
    acc[4] += a * kv1.x; acc[5] += a * kv1.y; acc[6] += a * kv1.z; acc[7] += a * kv1.w;
  }
  #pragma unroll
  for (int qd = 0; qd < 8; ++qd) {
    int c = cg0 + qd;
    size_t idx = ((size_t)b * NC + c) * NN + n0 + tn;
    outp[idx] = g * acc[qd] + x[idx];
  }
}

extern "C" void kernel_launch(void* const* d_in, const int* in_sizes, int n_in,
                              void* d_out, int out_size, void* d_ws, size_t ws_size,
                              hipStream_t stream) {
  const float* x     = (const float*)d_in[0];
  const float* wq    = (const float*)d_in[1];
  const float* bq    = (const float*)d_in[2];
  const float* wk    = (const float*)d_in[3];
  const float* bk    = (const float*)d_in[4];
  const float* wv    = (const float*)d_in[5];
  const float* bv    = (const float*)d_in[6];
  const float* gamma = (const float*)d_in[7];
  float* outp = (float*)d_out;                       // [B][C][N]
  float* attn = outp + (size_t)NB * NC * NN;         // [B][N][N]
  float* w = (float*)d_ws;

  float* qw   = w;                 // [B][N][D]    65536
  float* kw   = qw + 65536;        // [B][N][D]    65536
  float* vw   = kw + 65536;        // [B][C][N]    524288
  float* qlw  = vw + 524288;       // [B][M][D]    4096
  float* klw  = qlw + 4096;        // [B][M][D]    4096
  float* k1w  = klw + 4096;        // 8 MB region: k1bf (4MB) + k3bf (4MB)
  float* k2w  = k1w + 2097152;     // [B][M][M]    131072
  float* spare= k2w + 131072;      // (unused, keeps layout stable)
  float* Abuf = spare + 2097152;   // 4 MB region: Abf bf16
  float* Zb   = Abuf + 1048576;    // [B][M][M]    131072
  float* Z2b  = Zb + 131072;       // [B][M][M]    131072
  float* Ub   = Z2b + 131072;      // [B][M][M]    131072
  float* Va   = Ub + 131072;       // [B][M][M]    131072
  float* Vtw  = Va + 131072;       // Vinvt bf16   65536 floats
  float* kvw  = Vtw + 65536;       // [B][M][C]    32768
  float* denw = kvw + 32768;       // [2]
  ushort* k1bf  = (ushort*)k1w;                 // [B][N][M] bf16
  ushort* k3bf  = (ushort*)k1w + 2097152;       // [B][M][N] bf16 row-major
  ushort* Abf   = (ushort*)Abuf;                // [B][N][M] bf16
  ushort* Vinvt = (ushort*)Vtw;                 // [B][M][M] bf16 (Vinv^T)

  hipMemsetAsync(kvw, 0, (size_t)NB * NM * NC * sizeof(float), stream);
  qkv2_kernel<<<dim3(80, NN / 1024, NB), dim3(256), 0, stream>>>(
      x, wq, bq, wk, bk, wv, bv, qw, kw, vw);
  landmark_kernel<<<dim3(NB * NM * ND / 256), dim3(256), 0, stream>>>(qw, kw, qlw, klw);
  scores_softmax_m_bf16<<<dim3(NN / 4, NB), dim3(256), 0, stream>>>(qw, NN, klw, k1bf);
  scores_softmax_m_f32<<<dim3(NM / 4, NB), dim3(256), 0, stream>>>(qlw, NM, klw, k2w);
  scores_softmax_n<<<dim3(NM, NB), dim3(256), 0, stream>>>(qlw, kw, k3bf);
  denom_kernel<<<dim3(NB), dim3(256), 0, stream>>>(k2w, denw);
  vinit_kernel<<<dim3(NB * NM * NM / 256), dim3(256), 0, stream>>>(k2w, denw, Va);

  // Newton-Schulz via factored cubic (R7/R8-validated numerics): 18 launches.
  for (int it = 0; it < 6; ++it) {
    ns_z_kernel<<<dim3(NB * 64), dim3(256), 0, stream>>>(k2w, Va, Zb);
    ns_uz2_kernel<<<dim3(2 * NB * 64), dim3(256), 0, stream>>>(Va, Zb, Ub, Z2b);
    ns_v_kernel<<<dim3(NB * 64), dim3(256), 0, stream>>>(Ub, Z2b, Zb, Va);
  }

  cvt_vinv_kernel<<<dim3(NM / 32, NM / 32, NB), dim3(256), 0, stream>>>(Va, Vinvt);
  gemm_a_mfma<<<dim3(NM / 128, NN / 128, NB), dim3(256), 0, stream>>>(k1bf, Vinvt, Abf);
  gemm_attn_mfma<<<dim3(NN / 128, NN / 128, NB), dim3(256), 0, stream>>>(Abf, k3bf, attn);
  kv_kernel<<<dim3(NM / 64, 32, NB), dim3(256), 0, stream>>>(k3bf, vw, kvw);
  out_kernel<<<dim3(NB * NN / 32), dim3(256), 0, stream>>>(Abf, kvw, x, gamma, outp);
}